// Round 5
// baseline (695.075 us; speedup 1.0000x reference)
//
#include <hip/hip_runtime.h>

// NeuralIF GraphNet: 3 layers x (lower GraphNet, upper GraphNet).
// R1: bucketed edge lists + LDS-bin aggregation.
// R7: one-edge-per-thread edge kernel. 548us.
// R8 FAILED: global A/B tables, original edge order -> 139MB L3 gather.
// R9: bucket-permuted order; 4-array scatter write-amp (160MB) -> 120us.
// R10 FAILED: per-bucket edge blocks w/ 64KB LDS window -> occupancy 20%.
// R11: flat one-edge-per-thread edge kernel, 256-node buckets (32KB L1-sized
//      A-window), g+bias folded into Atab by nodew, XCD-chunked swizzle. 549us.
// R12 (this round): fuse mean-aggregation into the edge kernel via global
// float atomics (nsum[row] += out; L2-resident 400KB, bucket-clustered).
// aggnode_kernel (5x ~20us: re-read 17.6MB einfo + 4.4MB emb + 1.1M LDS
// atomics) replaced by slim per-node nodemlp_kernel (coalesced nsum/cnt/xf
// reads, MLP, nbins reduce) which also resets nsum to 0 for the next
// GraphNet (free memset). Degree counts computed once via atomics in the
// j=0/j=1 edge dispatches (COUNT flag).

typedef unsigned int u32;

#define NB_SHIFT 8
#define NB_SIZE 256
#define RSTRIDE 1104  // per-GraphNet region: ebins[64] nbins[64*16] pad

__device__ __forceinline__ float wave_sum(float v) {
#pragma unroll
    for (int off = 32; off > 0; off >>= 1) v += __shfl_down(v, off, 64);
    return v;
}

// ---------------- bucketed-list build (once per call) ----------------

__global__ __launch_bounds__(512) void hist_kernel(
    const int* __restrict__ lr, const int* __restrict__ ur,
    u32* __restrict__ hist, int E, int B) {
    __shared__ u32 h[512];
    const int t = threadIdx.x;
    if (t < B) h[t] = 0;
    __syncthreads();
    const int s = blockIdx.y;
    const int* rows = s ? ur : lr;
    for (int i = blockIdx.x * 512 + t; i < E; i += gridDim.x * 512)
        atomicAdd(&h[rows[i] >> NB_SHIFT], 1u);
    __syncthreads();
    if (t < B && h[t]) atomicAdd(&hist[s * B + t], h[t]);
}

// parallel exclusive scan of both segments (B <= 512), one block
__global__ __launch_bounds__(512) void scan_kernel(
    const u32* __restrict__ hist, u32* __restrict__ offs,
    u32* __restrict__ cur, int B) {
    __shared__ u32 sh[512];
    const int t = threadIdx.x;
    for (int s = 0; s < 2; ++s) {
        const u32 v = (t < B) ? hist[s * B + t] : 0u;
        sh[t] = v;
        __syncthreads();
#pragma unroll
        for (int off = 1; off < 512; off <<= 1) {
            const u32 add = (t >= off) ? sh[t - off] : 0u;
            __syncthreads();
            sh[t] += add;
            __syncthreads();
        }
        const u32 exc = sh[t] - v;
        if (t < B) {
            offs[s * (B + 1) + t] = exc;
            cur[s * B + t] = exc;
        }
        if (t == 511) offs[s * (B + 1) + B] = sh[511];
        __syncthreads();
    }
}

// scatter: build packed permuted edge records {row, col, eid, attr}
#define SCHUNK 4096
__global__ __launch_bounds__(512) void scatter_kernel(
    const int* __restrict__ lr, const int* __restrict__ lc,
    const int* __restrict__ ur, const int* __restrict__ uc,
    const float* __restrict__ la, const float* __restrict__ ua,
    u32* __restrict__ cur, uint4* __restrict__ einfo, int E, int B) {
    __shared__ u32 lcnt[512], lbase[512];
    const int t = threadIdx.x;
    const int s = blockIdx.y;
    const int* rows = s ? ur : lr;
    const int* cols = s ? uc : lc;
    const float* attr = s ? ua : la;
    uint4* my = einfo + (size_t)s * E;
    if (t < B) lcnt[t] = 0;
    __syncthreads();
    const int base_e = blockIdx.x * SCHUNK;
#pragma unroll
    for (int k = 0; k < SCHUNK / 512; ++k) {
        const int e = base_e + k * 512 + t;
        if (e < E) atomicAdd(&lcnt[rows[e] >> NB_SHIFT], 1u);
    }
    __syncthreads();
    if (t < B) {
        const u32 c = lcnt[t];
        lbase[t] = c ? atomicAdd(&cur[s * B + t], c) : 0u;
        lcnt[t] = 0;
    }
    __syncthreads();
#pragma unroll
    for (int k = 0; k < SCHUNK / 512; ++k) {
        const int e = base_e + k * 512 + t;
        if (e < E) {
            const int r = rows[e];
            const int b = r >> NB_SHIFT;
            const u32 pos = lbase[b] + atomicAdd(&lcnt[b], 1u);
            my[pos] = make_uint4((u32)r, (u32)cols[e], (u32)e,
                                 __float_as_uint(attr[e]));
        }
    }
}

// -------- per-node A-table with g+bias fold (and the g-MLP itself) --------
// Atab[n][j] = b1[j] + sum_k g[k]*W1[k,j] + sum_k x[n,k]*W1[8+k,j]
// Every block redundantly computes g (tiny); block 0 materializes gslot[j].

template <bool GCOMP>
__global__ __launch_bounds__(256) void nodew_kernel(
    const float4* __restrict__ xf, const float* __restrict__ W1,
    const float* __restrict__ b1,
    const float* __restrict__ gprev,   // gslot[j-1] (or gslot[0]=0)
    float* __restrict__ gout,          // gslot[j] (GCOMP: block0 writes)
    const float* __restrict__ pebins,  // prev region e-mean bins (GCOMP)
    const float* __restrict__ pnbins,  // prev region n-mean bins (GCOMP)
    const float* __restrict__ gW1, const float* __restrict__ gb1,
    const float* __restrict__ gW2, const float* __restrict__ gb2,
    float4* __restrict__ Atab, int N, float inv_E) {
    __shared__ float gsh[8];
    const int t = threadIdx.x;
    if constexpr (GCOMP) {
        if (t < 64) {  // wave 0: g = gMLP(n_mean, e_mean, g_prev)
            float nb[8];
#pragma unroll
            for (int q = 0; q < 8; ++q) nb[q] = pnbins[t * 16 + q];
            const float eb = pebins[t];
            float gin[17];
#pragma unroll
            for (int q = 0; q < 8; ++q) {
                const float s = wave_sum(nb[q]);
                gin[q] = __shfl(s, 0, 64) / (float)N;
            }
            const float es = wave_sum(eb);
            gin[8] = __shfl(es, 0, 64) * inv_E;
#pragma unroll
            for (int k = 0; k < 8; ++k) gin[9 + k] = gprev[k];
            float hv = 0.0f;
            if (t < 32) {
                hv = gb1[t];
#pragma unroll
                for (int k = 0; k < 17; ++k)
                    hv = fmaf(gin[k], gW1[k * 32 + t], hv);
                hv = fmaxf(hv, 0.0f);
            }
#pragma unroll
            for (int q = 0; q < 8; ++q) {
                const float c = (t < 32) ? hv * gW2[t * 8 + q] : 0.0f;
                const float s = wave_sum(c);
                if (t == 0) {
                    const float gv = gb2[q] + s;
                    gsh[q] = gv;
                    if (blockIdx.x == 0) gout[q] = gv;
                }
            }
        }
    } else {
        if (t < 8) gsh[t] = gprev[t];  // zeros for GraphNet 0
    }
    __syncthreads();
    const int n = blockIdx.x * 256 + t;
    if (n >= N) return;
    float gr[8];
#pragma unroll
    for (int k = 0; k < 8; ++k) gr[k] = gsh[k];
    const float4 x0 = xf[2 * (size_t)n], x1 = xf[2 * (size_t)n + 1];
    const float xs[8] = {x0.x, x0.y, x0.z, x0.w, x1.x, x1.y, x1.z, x1.w};
    float a[32];
#pragma unroll
    for (int j = 0; j < 32; ++j) {
        float v = b1[j];
#pragma unroll
        for (int k = 0; k < 8; ++k) v = fmaf(gr[k], W1[k * 32 + j], v);
        a[j] = v;
    }
    const float* __restrict__ WA = W1 + 8 * 32;
#pragma unroll
    for (int k = 0; k < 8; ++k) {
        const float v = xs[k];
#pragma unroll
        for (int j = 0; j < 32; ++j) a[j] = fmaf(v, WA[k * 32 + j], a[j]);
    }
    float4* An = Atab + 8 * (size_t)n;
#pragma unroll
    for (int q = 0; q < 8; ++q)
        An[q] = make_float4(a[4 * q], a[4 * q + 1], a[4 * q + 2], a[4 * q + 3]);
}

// ---------------- edge MLP: flat grid, one edge per thread ----------------
// Bucket-permuted order keeps Atab row-gathers inside a 32KB (L1-sized)
// window. XCD-chunked swizzle keeps each XCD's L2 on a contiguous Atab slice.
// NAGG: fused mean-aggregation via global atomics (nsum is L2-resident 400KB,
// bucket-clustered addresses). COUNT: degree atomics (j=0,1 only).

template <bool SKIP, bool FIRST, bool GAGG, bool VALS, bool STORE, bool NAGG,
          bool COUNT>
__global__ __launch_bounds__(256) void edge_kernel(
    const uint4* __restrict__ einfo,   // packed permuted records
    const float4* __restrict__ Atab,   // folded per-node partials
    const float4* __restrict__ xf,     // current node features (x or l_n)
    const float* __restrict__ eprev,   // prev edge emb (permuted), !FIRST
    const float* __restrict__ W1,      // 26x32 slice (row-major k,j)
    const float* __restrict__ W2,      // 32
    const float* __restrict__ b2,      // 1
    float* __restrict__ ebins,         // this region's e-mean bins (GAGG)
    float* __restrict__ e_out,         // edge emb store (permuted, STORE)
    float* __restrict__ vals_out,      // final output segment (VALS)
    float* __restrict__ nsum,          // per-node edge-emb sum (NAGG)
    float* __restrict__ ncnt,          // per-node degree (COUNT)
    int E, int cpx) {
    __shared__ float wpart[4];
    const int t = threadIdx.x;
    const int lid = (blockIdx.x & 7) * cpx + (blockIdx.x >> 3);
    const int i0 = lid * 256;
    if (i0 >= E) return;  // padded-grid tail block
    const int i = i0 + t;
    const bool valid = i < E;
    const int idx = valid ? i : i0;

    const uint4 e4 = einfo[idx];
    const float attr = __uint_as_float(e4.w);
    float epv;
    if constexpr (FIRST) epv = attr;
    else epv = eprev[idx];
    // A-row gather (8x16B inside this bucket's 32KB window)
    const float4* __restrict__ Ar = Atab + 8 * (size_t)e4.x;
    float h[32];
#pragma unroll
    for (int q = 0; q < 8; ++q) {
        const float4 av = Ar[q];
        h[4 * q + 0] = av.x; h[4 * q + 1] = av.y;
        h[4 * q + 2] = av.z; h[4 * q + 3] = av.w;
    }
    // col features (32B gather, L2-resident table)
    const float4 xc0 = xf[2 * (size_t)e4.y], xc1 = xf[2 * (size_t)e4.y + 1];
    const float cx[8] = {xc0.x, xc0.y, xc0.z, xc0.w,
                         xc1.x, xc1.y, xc1.z, xc1.w};
    const float* __restrict__ Wc = W1 + 16 * 32;  // col rows 16..23
#pragma unroll
    for (int k = 0; k < 8; ++k) {
        const float v = cx[k];
#pragma unroll
        for (int j = 0; j < 32; ++j) h[j] = fmaf(v, Wc[k * 32 + j], h[j]);
    }
    const float* __restrict__ W24 = W1 + 24 * 32;
#pragma unroll
    for (int j = 0; j < 32; ++j) h[j] = fmaf(epv, W24[j], h[j]);
    if constexpr (SKIP) {
        const float* __restrict__ W25 = W1 + 25 * 32;
#pragma unroll
        for (int j = 0; j < 32; ++j) h[j] = fmaf(attr, W25[j], h[j]);
    }
    float out = b2[0];
#pragma unroll
    for (int j = 0; j < 32; ++j) out = fmaf(fmaxf(h[j], 0.0f), W2[j], out);

    if (valid) {
        if constexpr (STORE) e_out[i] = out;
        if constexpr (VALS)
            vals_out[e4.z] = (e4.x == e4.y) ? expf(out) : out;
        if constexpr (NAGG) {
            atomicAdd(&nsum[e4.x], out);
            if constexpr (COUNT) atomicAdd(&ncnt[e4.x], 1.0f);
        }
    }
    if constexpr (GAGG) {
        const float s = wave_sum(valid ? out : 0.0f);
        if ((t & 63) == 0) wpart[t >> 6] = s;
        __syncthreads();
        if (t == 0)
            atomicAdd(&ebins[lid & 63],
                      wpart[0] + wpart[1] + wpart[2] + wpart[3]);
    }
}

// ------- slim per-node MLP: coalesced nsum/cnt/xf reads, nsum reset -------

template <bool STORE_N>
__global__ __launch_bounds__(256) void nodemlp_kernel(
    float* __restrict__ nsum,        // per-node sum (read, then reset to 0)
    const float* __restrict__ cntf,  // per-node degree
    const float4* __restrict__ xf,   // node features: x (lower) or l_n (upper)
    const float* __restrict__ g,     // gslot[j] (materialized)
    const float* __restrict__ nW1, const float* __restrict__ nb1,
    const float* __restrict__ nW2, const float* __restrict__ nb2,
    float* __restrict__ n_out,  // l_n (8N) if STORE_N
    float* __restrict__ nbins,  // 64 x 16 n-mean partial bins
    int N) {
    __shared__ float biasN[32];
    __shared__ float npart[4][8];
    const int t = threadIdx.x;
    if (t < 32) {
        float v = nb1[t];
#pragma unroll
        for (int k = 0; k < 8; ++k) v = fmaf(g[k], nW1[k * 32 + t], v);
        biasN[t] = v;
    }
    __syncthreads();
    const int n = blockIdx.x * 256 + t;
    const bool active = n < N;
    const int idx = active ? n : (N - 1);
    const float s = nsum[idx];
    if (active) nsum[idx] = 0.0f;  // free reset for the next GraphNet
    const float agg = s / fmaxf(cntf[idx], 1.0f);
    const float4 x0 = xf[2 * (size_t)idx], x1 = xf[2 * (size_t)idx + 1];
    float in[9] = {x0.x, x0.y, x0.z, x0.w, x1.x, x1.y, x1.z, x1.w, agg};
    float h[32];
#pragma unroll
    for (int j = 0; j < 8; ++j) {
        const float4 bb = reinterpret_cast<const float4*>(biasN)[j];
        h[4 * j + 0] = bb.x; h[4 * j + 1] = bb.y;
        h[4 * j + 2] = bb.z; h[4 * j + 3] = bb.w;
    }
    const float* __restrict__ Wk = nW1 + 8 * 32;
#pragma unroll
    for (int k = 0; k < 9; ++k) {
        const float v = in[k];
#pragma unroll
        for (int j = 0; j < 32; ++j) h[j] = fmaf(v, Wk[k * 32 + j], h[j]);
    }
    float o[8];
#pragma unroll
    for (int q = 0; q < 8; ++q) o[q] = nb2[q];
#pragma unroll
    for (int j = 0; j < 32; ++j) {
        const float hv = fmaxf(h[j], 0.0f);
#pragma unroll
        for (int q = 0; q < 8; ++q) o[q] = fmaf(hv, nW2[j * 8 + q], o[q]);
    }
    if constexpr (STORE_N) {
        if (active) {
            reinterpret_cast<float4*>(n_out)[2 * n] =
                make_float4(o[0], o[1], o[2], o[3]);
            reinterpret_cast<float4*>(n_out)[2 * n + 1] =
                make_float4(o[4], o[5], o[6], o[7]);
        }
    }
#pragma unroll
    for (int q = 0; q < 8; ++q) {
        const float s2 = wave_sum(active ? o[q] : 0.0f);
        if ((t & 63) == 0) npart[t >> 6][q] = s2;
    }
    __syncthreads();
    if (t < 8) {
        float a = 0.0f;
#pragma unroll
        for (int w = 0; w < 4; ++w) a += npart[w][t];
        atomicAdd(&nbins[(blockIdx.x & 63) * 16 + t], a);
    }
}

extern "C" void kernel_launch(void* const* d_in, const int* in_sizes, int n_in,
                              void* d_out, int out_size, void* d_ws,
                              size_t ws_size, hipStream_t stream) {
    const float* x = (const float*)d_in[0];
    const int* l_ei = (const int*)d_in[1];
    const int* u_ei = (const int*)d_in[2];
    const float* l_attr = (const float*)d_in[3];
    const float* u_attr = (const float*)d_in[4];
    const float* eW1 = (const float*)d_in[5];
    const float* eb1 = (const float*)d_in[6];
    const float* eW2 = (const float*)d_in[7];
    const float* eb2 = (const float*)d_in[8];
    const float* nW1 = (const float*)d_in[9];
    const float* nb1 = (const float*)d_in[10];
    const float* nW2 = (const float*)d_in[11];
    const float* nb2 = (const float*)d_in[12];
    const float* gW1 = (const float*)d_in[13];
    const float* gb1 = (const float*)d_in[14];
    const float* gW2 = (const float*)d_in[15];
    const float* gb2 = (const float*)d_in[16];

    const int E = in_sizes[3];      // 1,100,000
    const int N = in_sizes[0] / 8;  // 100,000
    const int B = (N + NB_SIZE - 1) >> NB_SHIFT;  // 391 buckets
    const int Ep = (E + 3) & ~3;    // float4-safe stride for emb arrays

    // workspace layout. einfo first (16B-aligned at base).
    uint4* einfo = (uint4*)d_ws;                   // 2E packed records
    float* Atab = (float*)(einfo + (size_t)2 * E); // 32N (folded partials)
    float* l_e = Atab + (size_t)32 * N;            // Ep
    float* u_e = l_e + Ep;                         // Ep
    float* l_n = u_e + Ep;                         // 8N (float4-aligned)
    // ---- zeroed region: cnt_l cnt_u nsum_l nsum_u gslot hist dyn_all ----
    float* cnt_l = l_n + (size_t)8 * N;            // N
    float* cnt_u = cnt_l + N;                      // N
    float* nsum_l = cnt_u + N;                     // N
    float* nsum_u = nsum_l + N;                    // N
    float* gslot = nsum_u + N;                     // 7 x 8
    u32* hist = (u32*)(gslot + 56);                // 2B
    float* dyn_all = (float*)(hist + 2 * B);       // 5 * RSTRIDE
    u32* offs = (u32*)(dyn_all + 5 * RSTRIDE);     // 2(B+1)
    u32* cur = offs + 2 * (B + 1);                 // 2B

    const int* lr = l_ei;
    const int* lc = l_ei + E;
    const int* ur = u_ei;
    const int* uc = u_ei + E;
    const int sg = (E + SCHUNK - 1) / SCHUNK;
    const int ng = (N + 255) / 256;
    const int eg = (E + 255) / 256;
    const int nwg8 = (eg + 7) & ~7;  // padded grid, %8 == 0 (bijective swz)
    const int cpx = nwg8 >> 3;
    const float invE = 1.0f / (float)E;
    float* outL = (float*)d_out;
    float* outU = outL + E;

    // one memset: counts + sums + gslots + hist + all 5 bin regions
    hipMemsetAsync(cnt_l, 0,
                   (size_t)(4 * N + 56 + 2 * B + 5 * RSTRIDE) * sizeof(float),
                   stream);
    hist_kernel<<<dim3(64, 2), 512, 0, stream>>>(lr, ur, hist, E, B);
    scan_kernel<<<1, 512, 0, stream>>>(hist, offs, cur, B);
    scatter_kernel<<<dim3(sg, 2), 512, 0, stream>>>(lr, lc, ur, uc, l_attr,
                                                    u_attr, cur, einfo, E, B);

    // weight-slice per GraphNet j: lower i -> i, upper i -> 3+i
    const size_t wsl[6] = {0, 3, 1, 4, 2, 5};

    for (int j = 0; j < 6; ++j) {
        const bool lower = !(j & 1);
        const size_t sl = wsl[j];
        float* ebins = dyn_all + (size_t)(j <= 4 ? j : 4) * RSTRIDE;
        float* nbins = ebins + 64;
        const float* pe = (j >= 1) ? dyn_all + (size_t)(j - 1) * RSTRIDE : nullptr;
        const float* pn = (j >= 1) ? pe + 64 : nullptr;
        const size_t psl = (j >= 1) ? wsl[j - 1] : 0;
        const float4* exf = (const float4*)(lower ? x : l_n);
        const uint4* einfo_t = einfo + (size_t)(lower ? 0 : 1) * E;
        const float* eprev = lower ? l_e : u_e;  // unused when FIRST
        float* e_out = lower ? l_e : u_e;
        float* nsum = lower ? nsum_l : nsum_u;
        float* cntf = lower ? cnt_l : cnt_u;
        const float* gprev = gslot + (size_t)(j >= 1 ? j - 1 : 0) * 8;
        float* gout = gslot + (size_t)j * 8;

        // folded per-node A-table (+ g-MLP; block0 materializes gslot[j])
        if (j == 0)
            nodew_kernel<false><<<ng, 256, 0, stream>>>(
                exf, eW1 + sl * 832, eb1 + sl * 32, gprev, gout, pe, pn,
                gW1, gb1, gW2, gb2, (float4*)Atab, N, invE);
        else
            nodew_kernel<true><<<ng, 256, 0, stream>>>(
                exf, eW1 + sl * 832, eb1 + sl * 32, gprev, gout, pe, pn,
                gW1 + psl * 544, gb1 + psl * 32, gW2 + psl * 256,
                gb2 + psl * 8, (float4*)Atab, N, invE);

#define EDGE_ARGS                                                             \
    einfo_t, (const float4*)Atab, exf, eprev, eW1 + sl * 832,                 \
        eW2 + sl * 32, eb2 + sl, ebins, e_out, (j == 4) ? outL : outU,        \
        nsum, cntf, E, cpx

        switch (j) {  // SKIP, FIRST, GAGG, VALS, STORE, NAGG, COUNT
            case 0: edge_kernel<false, true, true, false, true, true, true>
                        <<<nwg8, 256, 0, stream>>>(EDGE_ARGS); break;
            case 1: edge_kernel<false, true, true, false, true, true, true>
                        <<<nwg8, 256, 0, stream>>>(EDGE_ARGS); break;
            case 2: edge_kernel<true, false, true, false, true, true, false>
                        <<<nwg8, 256, 0, stream>>>(EDGE_ARGS); break;
            case 3: edge_kernel<false, false, true, false, true, true, false>
                        <<<nwg8, 256, 0, stream>>>(EDGE_ARGS); break;
            case 4: edge_kernel<true, false, true, true, true, true, false>
                        <<<nwg8, 256, 0, stream>>>(EDGE_ARGS); break;
            case 5: edge_kernel<false, false, false, true, false, false, false>
                        <<<nwg8, 256, 0, stream>>>(EDGE_ARGS); break;
        }
#undef EDGE_ARGS

        if (j == 5) break;  // final upper GraphNet: edge output only

        const float4* nxf = (const float4*)(lower ? x : l_n);

#define NODE_ARGS                                                             \
    nsum, cntf, nxf, gslot + (size_t)j * 8, nW1 + sl * 544, nb1 + sl * 32,    \
        nW2 + sl * 256, nb2 + sl * 8, l_n, nbins, N

        switch (j) {  // STORE_N
            case 0: nodemlp_kernel<true>
                        <<<ng, 256, 0, stream>>>(NODE_ARGS); break;
            case 1: nodemlp_kernel<false>
                        <<<ng, 256, 0, stream>>>(NODE_ARGS); break;
            case 2: nodemlp_kernel<true>
                        <<<ng, 256, 0, stream>>>(NODE_ARGS); break;
            case 3: nodemlp_kernel<false>
                        <<<ng, 256, 0, stream>>>(NODE_ARGS); break;
            case 4: nodemlp_kernel<true>
                        <<<ng, 256, 0, stream>>>(NODE_ARGS); break;
        }
#undef NODE_ARGS
    }
}

// Round 7
// 508.883 us; speedup vs baseline: 1.3659x; 1.3659x over previous
//
#include <hip/hip_runtime.h>

// NeuralIF GraphNet: 3 layers x (lower GraphNet, upper GraphNet).
// R7: one-edge-per-thread edge kernel. 548us.
// R8 FAILED: global A/B tables, original edge order -> 139MB L3 gather.
// R9: bucket-permuted order; 4-array scatter write-amp (160MB) -> 120us.
// R10 FAILED: per-bucket edge blocks w/ 64KB LDS window -> occupancy 20%.
// R11: flat one-edge-per-thread edge kernel, 256-node buckets, g+bias folded
//      into Atab, XCD-chunked swizzle. 549us.
// R12 FAILED: fused aggregation via global nsum[row] atomics (cross-XCD RMW
//      ping-pong; edge 99us).
// R13 FAILED (container fault x2): full row sort + CSR nodemlp, but workspace
//      layout needed ~71.3MB (einfo2 2E + tmp 2E) — likely past ws_size;
//      tail arrays (row_offs/dyn) written OOB -> reproducible GPU fault.
// R14 (this round): R13 design at R12's known-good footprint (~61.3MB).
//  - tmp bucket-order buffer is E records; scatter+sort run per segment
//    sequentially (lower fully drains tmp into einfo2 before upper reuses it).
//  - Atab (12.8MB) + l_e (4.4MB) alias the dead tmp slot; u_e/l_n/small after.
//  - Row-sorted edge kernel (A-row gathers = L1 broadcasts), CSR nodemlp
//    (contiguous segment sum, no atomics), folded nodew, XCD swizzle: as R13.

typedef unsigned int u32;

#define NB_SHIFT 8
#define NB_SIZE 256
#define RSTRIDE 1104  // per-GraphNet region: ebins[64] nbins[64*16] pad

__device__ __forceinline__ float wave_sum(float v) {
#pragma unroll
    for (int off = 32; off > 0; off >>= 1) v += __shfl_down(v, off, 64);
    return v;
}

// ---------------- bucketed-list build (once per call) ----------------

__global__ __launch_bounds__(512) void hist_kernel(
    const int* __restrict__ lr, const int* __restrict__ ur,
    u32* __restrict__ hist, int E, int B) {
    __shared__ u32 h[512];
    const int t = threadIdx.x;
    if (t < B) h[t] = 0;
    __syncthreads();
    const int s = blockIdx.y;
    const int* rows = s ? ur : lr;
    for (int i = blockIdx.x * 512 + t; i < E; i += gridDim.x * 512)
        atomicAdd(&h[rows[i] >> NB_SHIFT], 1u);
    __syncthreads();
    if (t < B && h[t]) atomicAdd(&hist[s * B + t], h[t]);
}

// parallel exclusive scan of both segments (B <= 512), one block
__global__ __launch_bounds__(512) void scan_kernel(
    const u32* __restrict__ hist, u32* __restrict__ offs,
    u32* __restrict__ cur, int B) {
    __shared__ u32 sh[512];
    const int t = threadIdx.x;
    for (int s = 0; s < 2; ++s) {
        const u32 v = (t < B) ? hist[s * B + t] : 0u;
        sh[t] = v;
        __syncthreads();
#pragma unroll
        for (int off = 1; off < 512; off <<= 1) {
            const u32 add = (t >= off) ? sh[t - off] : 0u;
            __syncthreads();
            sh[t] += add;
            __syncthreads();
        }
        const u32 exc = sh[t] - v;
        if (t < B) {
            offs[s * (B + 1) + t] = exc;
            cur[s * B + t] = exc;
        }
        if (t == 511) offs[s * (B + 1) + B] = sh[511];
        __syncthreads();
    }
}

// scatter ONE segment: packed bucket-permuted records {row, col, eid, attr}
#define SCHUNK 4096
__global__ __launch_bounds__(512) void scatter_kernel(
    const int* __restrict__ rows, const int* __restrict__ cols,
    const float* __restrict__ attr, u32* __restrict__ cur,
    uint4* __restrict__ my, int E, int B) {
    __shared__ u32 lcnt[512], lbase[512];
    const int t = threadIdx.x;
    if (t < B) lcnt[t] = 0;
    __syncthreads();
    const int base_e = blockIdx.x * SCHUNK;
#pragma unroll
    for (int k = 0; k < SCHUNK / 512; ++k) {
        const int e = base_e + k * 512 + t;
        if (e < E) atomicAdd(&lcnt[rows[e] >> NB_SHIFT], 1u);
    }
    __syncthreads();
    if (t < B) {
        const u32 c = lcnt[t];
        lbase[t] = c ? atomicAdd(&cur[t], c) : 0u;
        lcnt[t] = 0;
    }
    __syncthreads();
#pragma unroll
    for (int k = 0; k < SCHUNK / 512; ++k) {
        const int e = base_e + k * 512 + t;
        if (e < E) {
            const int r = rows[e];
            const int b = r >> NB_SHIFT;
            const u32 pos = lbase[b] + atomicAdd(&lcnt[b], 1u);
            my[pos] = make_uint4((u32)r, (u32)cols[e], (u32)e,
                                 __float_as_uint(attr[e]));
        }
    }
}

// ---- per-bucket LDS counting sort (one segment): bucket -> row order ----
// Also emits per-node CSR offsets (row_offs). One block per bucket.

__global__ __launch_bounds__(512) void sort_kernel(
    const uint4* __restrict__ in, uint4* __restrict__ out,
    const u32* __restrict__ offs, u32* __restrict__ row_offs,
    int E, int N) {
    __shared__ u32 cnt[NB_SIZE];
    __shared__ u32 scn[NB_SIZE];
    const int t = threadIdx.x;
    const int b = blockIdx.x;
    const u32 beg = offs[b], end = offs[b + 1];
    if (t < NB_SIZE) cnt[t] = 0;
    __syncthreads();
    for (u32 i = beg + t; i < end; i += 512)
        atomicAdd(&cnt[in[i].x & (NB_SIZE - 1)], 1u);
    __syncthreads();
    if (t < NB_SIZE) scn[t] = cnt[t];
    __syncthreads();
#pragma unroll
    for (int off = 1; off < NB_SIZE; off <<= 1) {
        u32 add = 0;
        if (t < NB_SIZE && t >= off) add = scn[t - off];
        __syncthreads();
        if (t < NB_SIZE) scn[t] += add;
        __syncthreads();
    }
    const int n0 = b << NB_SHIFT;
    if (t < NB_SIZE) {
        const u32 excl = scn[t] - cnt[t];
        if (n0 + t < N) row_offs[n0 + t] = beg + excl;
        cnt[t] = excl;  // reuse as write cursor
    }
    if (b == 0 && t == 0) row_offs[N] = (u32)E;
    __syncthreads();
    for (u32 i = beg + t; i < end; i += 512) {
        const uint4 r = in[i];
        const u32 pos = beg + atomicAdd(&cnt[r.x & (NB_SIZE - 1)], 1u);
        out[pos] = r;
    }
}

// -------- per-node A-table with g+bias fold (and the g-MLP itself) --------
// Atab[n][j] = b1[j] + sum_k g[k]*W1[k,j] + sum_k x[n,k]*W1[8+k,j]
// Every block redundantly computes g (tiny); block 0 materializes gslot[j].

template <bool GCOMP>
__global__ __launch_bounds__(256) void nodew_kernel(
    const float4* __restrict__ xf, const float* __restrict__ W1,
    const float* __restrict__ b1,
    const float* __restrict__ gprev,   // gslot[j-1] (or gslot[0]=0)
    float* __restrict__ gout,          // gslot[j] (GCOMP: block0 writes)
    const float* __restrict__ pebins,  // prev region e-mean bins (GCOMP)
    const float* __restrict__ pnbins,  // prev region n-mean bins (GCOMP)
    const float* __restrict__ gW1, const float* __restrict__ gb1,
    const float* __restrict__ gW2, const float* __restrict__ gb2,
    float4* __restrict__ Atab, int N, float inv_E) {
    __shared__ float gsh[8];
    const int t = threadIdx.x;
    if constexpr (GCOMP) {
        if (t < 64) {  // wave 0: g = gMLP(n_mean, e_mean, g_prev)
            float nb[8];
#pragma unroll
            for (int q = 0; q < 8; ++q) nb[q] = pnbins[t * 16 + q];
            const float eb = pebins[t];
            float gin[17];
#pragma unroll
            for (int q = 0; q < 8; ++q) {
                const float s = wave_sum(nb[q]);
                gin[q] = __shfl(s, 0, 64) / (float)N;
            }
            const float es = wave_sum(eb);
            gin[8] = __shfl(es, 0, 64) * inv_E;
#pragma unroll
            for (int k = 0; k < 8; ++k) gin[9 + k] = gprev[k];
            float hv = 0.0f;
            if (t < 32) {
                hv = gb1[t];
#pragma unroll
                for (int k = 0; k < 17; ++k)
                    hv = fmaf(gin[k], gW1[k * 32 + t], hv);
                hv = fmaxf(hv, 0.0f);
            }
#pragma unroll
            for (int q = 0; q < 8; ++q) {
                const float c = (t < 32) ? hv * gW2[t * 8 + q] : 0.0f;
                const float s = wave_sum(c);
                if (t == 0) {
                    const float gv = gb2[q] + s;
                    gsh[q] = gv;
                    if (blockIdx.x == 0) gout[q] = gv;
                }
            }
        }
    } else {
        if (t < 8) gsh[t] = gprev[t];  // zeros for GraphNet 0
    }
    __syncthreads();
    const int n = blockIdx.x * 256 + t;
    if (n >= N) return;
    float gr[8];
#pragma unroll
    for (int k = 0; k < 8; ++k) gr[k] = gsh[k];
    const float4 x0 = xf[2 * (size_t)n], x1 = xf[2 * (size_t)n + 1];
    const float xs[8] = {x0.x, x0.y, x0.z, x0.w, x1.x, x1.y, x1.z, x1.w};
    float a[32];
#pragma unroll
    for (int j = 0; j < 32; ++j) {
        float v = b1[j];
#pragma unroll
        for (int k = 0; k < 8; ++k) v = fmaf(gr[k], W1[k * 32 + j], v);
        a[j] = v;
    }
    const float* __restrict__ WA = W1 + 8 * 32;
#pragma unroll
    for (int k = 0; k < 8; ++k) {
        const float v = xs[k];
#pragma unroll
        for (int j = 0; j < 32; ++j) a[j] = fmaf(v, WA[k * 32 + j], a[j]);
    }
    float4* An = Atab + 8 * (size_t)n;
#pragma unroll
    for (int q = 0; q < 8; ++q)
        An[q] = make_float4(a[4 * q], a[4 * q + 1], a[4 * q + 2], a[4 * q + 3]);
}

// ---------------- edge MLP: flat grid, one edge per thread ----------------
// Row-sorted order: consecutive lanes mostly share the same row -> A-row
// gathers are L1 broadcasts. XCD-chunked swizzle keeps each XCD's L2 on a
// contiguous Atab slice.

template <bool SKIP, bool FIRST, bool GAGG, bool VALS, bool STORE>
__global__ __launch_bounds__(256) void edge_kernel(
    const uint4* __restrict__ einfo,   // packed row-sorted records
    const float4* __restrict__ Atab,   // folded per-node partials
    const float4* __restrict__ xf,     // current node features (x or l_n)
    const float* __restrict__ eprev,   // prev edge emb (permuted), !FIRST
    const float* __restrict__ W1,      // 26x32 slice (row-major k,j)
    const float* __restrict__ W2,      // 32
    const float* __restrict__ b2,      // 1
    float* __restrict__ ebins,         // this region's e-mean bins (GAGG)
    float* __restrict__ e_out,         // edge emb store (permuted, STORE)
    float* __restrict__ vals_out,      // final output segment (VALS)
    int E, int cpx) {
    __shared__ float wpart[4];
    const int t = threadIdx.x;
    const int lid = (blockIdx.x & 7) * cpx + (blockIdx.x >> 3);
    const int i0 = lid * 256;
    if (i0 >= E) return;  // padded-grid tail block
    const int i = i0 + t;
    const bool valid = i < E;
    const int idx = valid ? i : i0;

    const uint4 e4 = einfo[idx];
    const float attr = __uint_as_float(e4.w);
    float epv;
    if constexpr (FIRST) epv = attr;
    else epv = eprev[idx];
    // A-row gather (8x16B; consecutive lanes share rows -> broadcast)
    const float4* __restrict__ Ar = Atab + 8 * (size_t)e4.x;
    float h[32];
#pragma unroll
    for (int q = 0; q < 8; ++q) {
        const float4 av = Ar[q];
        h[4 * q + 0] = av.x; h[4 * q + 1] = av.y;
        h[4 * q + 2] = av.z; h[4 * q + 3] = av.w;
    }
    // col features (32B gather, L2-resident table)
    const float4 xc0 = xf[2 * (size_t)e4.y], xc1 = xf[2 * (size_t)e4.y + 1];
    const float cx[8] = {xc0.x, xc0.y, xc0.z, xc0.w,
                         xc1.x, xc1.y, xc1.z, xc1.w};
    const float* __restrict__ Wc = W1 + 16 * 32;  // col rows 16..23
#pragma unroll
    for (int k = 0; k < 8; ++k) {
        const float v = cx[k];
#pragma unroll
        for (int j = 0; j < 32; ++j) h[j] = fmaf(v, Wc[k * 32 + j], h[j]);
    }
    const float* __restrict__ W24 = W1 + 24 * 32;
#pragma unroll
    for (int j = 0; j < 32; ++j) h[j] = fmaf(epv, W24[j], h[j]);
    if constexpr (SKIP) {
        const float* __restrict__ W25 = W1 + 25 * 32;
#pragma unroll
        for (int j = 0; j < 32; ++j) h[j] = fmaf(attr, W25[j], h[j]);
    }
    float out = b2[0];
#pragma unroll
    for (int j = 0; j < 32; ++j) out = fmaf(fmaxf(h[j], 0.0f), W2[j], out);

    if (valid) {
        if constexpr (STORE) e_out[i] = out;
        if constexpr (VALS)
            vals_out[e4.z] = (e4.x == e4.y) ? expf(out) : out;
    }
    if constexpr (GAGG) {
        const float s = wave_sum(valid ? out : 0.0f);
        if ((t & 63) == 0) wpart[t >> 6] = s;
        __syncthreads();
        if (t == 0)
            atomicAdd(&ebins[lid & 63],
                      wpart[0] + wpart[1] + wpart[2] + wpart[3]);
    }
}

// -- slim per-node MLP: CSR segment sum (contiguous, no atomics) + MLP --

template <bool STORE_N>
__global__ __launch_bounds__(256) void nodemlp_kernel(
    const float* __restrict__ ep,      // row-sorted edge embeddings
    const u32* __restrict__ row_offs,  // N+1 CSR offsets
    const float4* __restrict__ xf,   // node features: x (lower) or l_n (upper)
    const float* __restrict__ g,     // gslot[j] (materialized)
    const float* __restrict__ nW1, const float* __restrict__ nb1,
    const float* __restrict__ nW2, const float* __restrict__ nb2,
    float* __restrict__ n_out,  // l_n (8N) if STORE_N
    float* __restrict__ nbins,  // 64 x 16 n-mean partial bins
    int N) {
    __shared__ float biasN[32];
    __shared__ float npart[4][8];
    const int t = threadIdx.x;
    if (t < 32) {
        float v = nb1[t];
#pragma unroll
        for (int k = 0; k < 8; ++k) v = fmaf(g[k], nW1[k * 32 + t], v);
        biasN[t] = v;
    }
    __syncthreads();
    const int n = blockIdx.x * 256 + t;
    const bool active = n < N;
    const int idx = active ? n : (N - 1);
    const u32 beg = row_offs[idx], end = row_offs[idx + 1];
    float ssum = 0.0f;
    for (u32 i = beg; i < end; ++i) ssum += ep[i];
    const float agg = ssum / fmaxf((float)(end - beg), 1.0f);
    const float4 x0 = xf[2 * (size_t)idx], x1 = xf[2 * (size_t)idx + 1];
    float in[9] = {x0.x, x0.y, x0.z, x0.w, x1.x, x1.y, x1.z, x1.w, agg};
    float h[32];
#pragma unroll
    for (int j = 0; j < 8; ++j) {
        const float4 bb = reinterpret_cast<const float4*>(biasN)[j];
        h[4 * j + 0] = bb.x; h[4 * j + 1] = bb.y;
        h[4 * j + 2] = bb.z; h[4 * j + 3] = bb.w;
    }
    const float* __restrict__ Wk = nW1 + 8 * 32;
#pragma unroll
    for (int k = 0; k < 9; ++k) {
        const float v = in[k];
#pragma unroll
        for (int j = 0; j < 32; ++j) h[j] = fmaf(v, Wk[k * 32 + j], h[j]);
    }
    float o[8];
#pragma unroll
    for (int q = 0; q < 8; ++q) o[q] = nb2[q];
#pragma unroll
    for (int j = 0; j < 32; ++j) {
        const float hv = fmaxf(h[j], 0.0f);
#pragma unroll
        for (int q = 0; q < 8; ++q) o[q] = fmaf(hv, nW2[j * 8 + q], o[q]);
    }
    if constexpr (STORE_N) {
        if (active) {
            reinterpret_cast<float4*>(n_out)[2 * n] =
                make_float4(o[0], o[1], o[2], o[3]);
            reinterpret_cast<float4*>(n_out)[2 * n + 1] =
                make_float4(o[4], o[5], o[6], o[7]);
        }
    }
#pragma unroll
    for (int q = 0; q < 8; ++q) {
        const float s2 = wave_sum(active ? o[q] : 0.0f);
        if ((t & 63) == 0) npart[t >> 6][q] = s2;
    }
    __syncthreads();
    if (t < 8) {
        float a = 0.0f;
#pragma unroll
        for (int w = 0; w < 4; ++w) a += npart[w][t];
        atomicAdd(&nbins[(blockIdx.x & 63) * 16 + t], a);
    }
}

extern "C" void kernel_launch(void* const* d_in, const int* in_sizes, int n_in,
                              void* d_out, int out_size, void* d_ws,
                              size_t ws_size, hipStream_t stream) {
    const float* x = (const float*)d_in[0];
    const int* l_ei = (const int*)d_in[1];
    const int* u_ei = (const int*)d_in[2];
    const float* l_attr = (const float*)d_in[3];
    const float* u_attr = (const float*)d_in[4];
    const float* eW1 = (const float*)d_in[5];
    const float* eb1 = (const float*)d_in[6];
    const float* eW2 = (const float*)d_in[7];
    const float* eb2 = (const float*)d_in[8];
    const float* nW1 = (const float*)d_in[9];
    const float* nb1 = (const float*)d_in[10];
    const float* nW2 = (const float*)d_in[11];
    const float* nb2 = (const float*)d_in[12];
    const float* gW1 = (const float*)d_in[13];
    const float* gb1 = (const float*)d_in[14];
    const float* gW2 = (const float*)d_in[15];
    const float* gb2 = (const float*)d_in[16];

    const int E = in_sizes[3];      // 1,100,000
    const int N = in_sizes[0] / 8;  // 100,000
    const int B = (N + NB_SIZE - 1) >> NB_SHIFT;  // 391 buckets
    const int Ep = (E + 3) & ~3;    // float4-safe stride for emb arrays

    // workspace layout (~61.3MB total, <= R12's known-good footprint):
    //  [einfo2 (sorted, persistent) 2E = 35.2MB]
    //  [tmp (bucket order, E recs = 17.6MB; dead after sorts)
    //     -> aliased by Atab (12.8MB) + l_e (4.4MB) = 17.2MB ]
    //  [u_e 4.4MB][l_n 3.2MB][gslot|hist|dyn|offs|cur|row_offs ~0.9MB]
    uint4* einfo2 = (uint4*)d_ws;                  // 2E sorted records
    uint4* tmp = einfo2 + (size_t)2 * E;           // E tmp records
    float* Atab = (float*)tmp;                     // alias (post-sort)
    float* l_e = Atab + (size_t)32 * N;            // Ep (alias, fits in tmp)
    float* u_e = (float*)(tmp + (size_t)E);        // Ep
    float* l_n = u_e + Ep;                         // 8N
    float* gslot = l_n + (size_t)8 * N;            // 7 x 8
    u32* hist = (u32*)(gslot + 56);                // 2B
    float* dyn_all = (float*)(hist + 2 * B);       // 5 * RSTRIDE
    u32* offs = (u32*)(dyn_all + 5 * RSTRIDE);     // 2(B+1)
    u32* cur = offs + 2 * (B + 1);                 // 2B
    u32* row_offs = cur + 2 * B;                   // 2(N+1) CSR offsets

    const int* lr = l_ei;
    const int* lc = l_ei + E;
    const int* ur = u_ei;
    const int* uc = u_ei + E;
    const int sg = (E + SCHUNK - 1) / SCHUNK;
    const int ng = (N + 255) / 256;
    const int eg = (E + 255) / 256;
    const int nwg8 = (eg + 7) & ~7;  // padded grid, %8 == 0 (bijective swz)
    const int cpx = nwg8 >> 3;
    const float invE = 1.0f / (float)E;
    float* outL = (float*)d_out;
    float* outU = outL + E;

    // one memset: gslots + hist + all 5 bin regions
    hipMemsetAsync(gslot, 0, (size_t)(56 + 2 * B + 5 * RSTRIDE) * sizeof(float),
                   stream);
    hist_kernel<<<dim3(64, 2), 512, 0, stream>>>(lr, ur, hist, E, B);
    scan_kernel<<<1, 512, 0, stream>>>(hist, offs, cur, B);
    // per-segment scatter+sort, sequential (tmp holds ONE segment at a time)
    scatter_kernel<<<sg, 512, 0, stream>>>(lr, lc, l_attr, cur, tmp, E, B);
    sort_kernel<<<B, 512, 0, stream>>>(tmp, einfo2, offs, row_offs, E, N);
    scatter_kernel<<<sg, 512, 0, stream>>>(ur, uc, u_attr, cur + B, tmp, E, B);
    sort_kernel<<<B, 512, 0, stream>>>(tmp, einfo2 + (size_t)E, offs + (B + 1),
                                       row_offs + (N + 1), E, N);

    // weight-slice per GraphNet j: lower i -> i, upper i -> 3+i
    const size_t wsl[6] = {0, 3, 1, 4, 2, 5};

    for (int j = 0; j < 6; ++j) {
        const bool lower = !(j & 1);
        const size_t sl = wsl[j];
        float* ebins = dyn_all + (size_t)(j <= 4 ? j : 4) * RSTRIDE;
        float* nbins = ebins + 64;
        const float* pe = (j >= 1) ? dyn_all + (size_t)(j - 1) * RSTRIDE : nullptr;
        const float* pn = (j >= 1) ? pe + 64 : nullptr;
        const size_t psl = (j >= 1) ? wsl[j - 1] : 0;
        const float4* exf = (const float4*)(lower ? x : l_n);
        const uint4* einfo_t = einfo2 + (size_t)(lower ? 0 : 1) * E;
        const u32* roffs = row_offs + (size_t)(lower ? 0 : 1) * (N + 1);
        const float* eprev = lower ? l_e : u_e;  // unused when FIRST
        float* e_out = lower ? l_e : u_e;
        const float* gprev = gslot + (size_t)(j >= 1 ? j - 1 : 0) * 8;
        float* gout = gslot + (size_t)j * 8;

        // folded per-node A-table (+ g-MLP; block0 materializes gslot[j])
        if (j == 0)
            nodew_kernel<false><<<ng, 256, 0, stream>>>(
                exf, eW1 + sl * 832, eb1 + sl * 32, gprev, gout, pe, pn,
                gW1, gb1, gW2, gb2, (float4*)Atab, N, invE);
        else
            nodew_kernel<true><<<ng, 256, 0, stream>>>(
                exf, eW1 + sl * 832, eb1 + sl * 32, gprev, gout, pe, pn,
                gW1 + psl * 544, gb1 + psl * 32, gW2 + psl * 256,
                gb2 + psl * 8, (float4*)Atab, N, invE);

#define EDGE_ARGS                                                             \
    einfo_t, (const float4*)Atab, exf, eprev, eW1 + sl * 832,                 \
        eW2 + sl * 32, eb2 + sl, ebins, e_out, (j == 4) ? outL : outU, E, cpx

        switch (j) {  // SKIP, FIRST, GAGG, VALS, STORE
            case 0: edge_kernel<false, true, true, false, true>
                        <<<nwg8, 256, 0, stream>>>(EDGE_ARGS); break;
            case 1: edge_kernel<false, true, true, false, true>
                        <<<nwg8, 256, 0, stream>>>(EDGE_ARGS); break;
            case 2: edge_kernel<true, false, true, false, true>
                        <<<nwg8, 256, 0, stream>>>(EDGE_ARGS); break;
            case 3: edge_kernel<false, false, true, false, true>
                        <<<nwg8, 256, 0, stream>>>(EDGE_ARGS); break;
            case 4: edge_kernel<true, false, true, true, true>
                        <<<nwg8, 256, 0, stream>>>(EDGE_ARGS); break;
            case 5: edge_kernel<false, false, false, true, false>
                        <<<nwg8, 256, 0, stream>>>(EDGE_ARGS); break;
        }
#undef EDGE_ARGS

        if (j == 5) break;  // final upper GraphNet: edge output only

        const float4* nxf = (const float4*)(lower ? x : l_n);

#define NODE_ARGS                                                             \
    e_out, roffs, nxf, gslot + (size_t)j * 8, nW1 + sl * 544, nb1 + sl * 32,  \
        nW2 + sl * 256, nb2 + sl * 8, l_n, nbins, N

        switch (j) {  // STORE_N
            case 0: nodemlp_kernel<true>
                        <<<ng, 256, 0, stream>>>(NODE_ARGS); break;
            case 1: nodemlp_kernel<false>
                        <<<ng, 256, 0, stream>>>(NODE_ARGS); break;
            case 2: nodemlp_kernel<true>
                        <<<ng, 256, 0, stream>>>(NODE_ARGS); break;
            case 3: nodemlp_kernel<false>
                        <<<ng, 256, 0, stream>>>(NODE_ARGS); break;
            case 4: nodemlp_kernel<true>
                        <<<ng, 256, 0, stream>>>(NODE_ARGS); break;
        }
#undef NODE_ARGS
    }
}